// Round 5
// baseline (259.008 us; speedup 1.0000x reference)
//
#include <hip/hip_runtime.h>

#define NB 32
#define NC 256
#define NH 64
#define NW 64
#define NK 16
#define HW (NH * NW)  // 4096

typedef float f32x4 __attribute__((ext_vector_type(4)));

__device__ __forceinline__ float fsig(float z) {
    // sigmoid(z) = 1/(1+exp(-z)); fast exp + hw rcp (vs 5.9e-2 threshold: plenty)
    return __builtin_amdgcn_rcpf(1.0f + __expf(-z));
}

// ---------------- kernel 1: s[b,h,w] = mean_c x[b,c,h,w]  (pure read stream) ----
__global__ __launch_bounds__(256, 8) void pse_mean(
    const float* __restrict__ x, float* __restrict__ s)
{
    __shared__ f32x4 part[16][17];
    const int t  = threadIdx.x;
    const int cg = t >> 4;   // 16 channels each
    const int q  = t & 15;   // w-quad

    const int bh = blockIdx.x;            // 0..2047
    const int b  = bh >> 6;
    const int h  = bh & 63;

    const float* __restrict__ xr =
        x + (size_t)b * NC * HW + (size_t)(cg << 4) * HW + (size_t)h * NW + (q << 2);

    // regular (cache-retaining) loads: we WANT x resident in L3 for pse_apply
    f32x4 p = (f32x4)(0.f);
    #pragma unroll
    for (int i = 0; i < 16; ++i)
        p += *reinterpret_cast<const f32x4*>(xr + (size_t)i * HW);
    part[cg][q] = p;
    __syncthreads();

    if (t < 16) {
        f32x4 acc = (f32x4)(0.f);
        #pragma unroll
        for (int i = 0; i < 16; ++i) acc += part[i][t];
        acc *= (1.0f / (float)NC);
        reinterpret_cast<f32x4*>(s)[bh * 16 + t] = acc;
    }
}

// ---------------- kernel 2: out = x * sigmoid(w2·relu(s*w1+b1) + b2) ------------
// Zero LDS, zero barriers: wave = (b,h, 64-channel group), lane = w.
// hv[16] computed redundantly per lane; w2 rows are wave-uniform -> scalar loads.
__global__ __launch_bounds__(256, 8) void pse_apply(
    const float* __restrict__ x, const float* __restrict__ s,
    const float* __restrict__ w1, const float* __restrict__ b1,
    const float* __restrict__ w2, const float* __restrict__ b2,
    float* __restrict__ out)
{
    const int t  = threadIdx.x;
    const int w  = t & 63;                                    // lane = w column
    const int cg = __builtin_amdgcn_readfirstlane(t >> 6);    // 0..3, wave-uniform

    const int bh = blockIdx.x;
    const int b  = bh >> 6;
    const int h  = bh & 63;

    // per-pixel hidden layer (redundant across lanes of other waves, VALU-cheap)
    const float sv = s[bh * NW + w];
    float hv[NK];
    #pragma unroll
    for (int k = 0; k < NK; ++k)
        hv[k] = fmaxf(fmaf(sv, w1[k], b1[k]), 0.f);

    const size_t base = (size_t)b * NC * HW + (size_t)(cg << 6) * HW
                      + (size_t)h * NW + w;
    const float* __restrict__ xp = x + base;
    float* __restrict__ op       = out + base;

    #pragma unroll 8
    for (int c = 0; c < 64; ++c) {
        const float xvv = xp[(size_t)c * HW];                 // L3-resident read
        const int ch = (cg << 6) + c;                         // wave-uniform
        const float* __restrict__ wr = w2 + ch * NK;          // s_load'able row
        float acc = b2[ch];
        #pragma unroll
        for (int k = 0; k < NK; ++k) acc = fmaf(hv[k], wr[k], acc);
        __builtin_nontemporal_store(xvv * fsig(acc), op + (size_t)c * HW);
    }
}

// ---------------- fallback (ws too small): R4 fused single-pass ------------------
__global__ __launch_bounds__(1024, 8) void pse_fused(
    const float* __restrict__ x,
    const float* __restrict__ w1, const float* __restrict__ b1,
    const float* __restrict__ w2, const float* __restrict__ b2,
    float* __restrict__ out)
{
    __shared__ float w2t[NK][NC + 4];
    __shared__ f32x4 part[64][17];
    __shared__ f32x4 sA[16][17];
    __shared__ f32x4 hv4[NK][16];
    __shared__ float b2s[NC];

    const int t  = threadIdx.x;
    const int cg = t >> 4;
    const int q  = t & 15;
    const int bh = blockIdx.x;
    const int b  = bh >> 6;
    const int h  = bh & 63;

    const size_t base = (size_t)b * NC * HW + (size_t)h * NW;
    const float* __restrict__ xp = x + base;
    float* __restrict__ op       = out + base;
    const float* __restrict__ xr = xp + (size_t)(cg << 2) * HW + (q << 2);

    f32x4 xv[4];
    #pragma unroll
    for (int i = 0; i < 4; ++i)
        xv[i] = __builtin_nontemporal_load(
            reinterpret_cast<const f32x4*>(xr + (size_t)i * HW));

    {
        const f32x4 v = reinterpret_cast<const f32x4*>(w2)[t];
        const int c  = t >> 2;
        const int k0 = (t & 3) << 2;
        w2t[k0 + 0][c] = v.x; w2t[k0 + 1][c] = v.y;
        w2t[k0 + 2][c] = v.z; w2t[k0 + 3][c] = v.w;
        if (t < NC) b2s[t] = b2[t];
    }

    part[cg][q] = xv[0] + xv[1] + xv[2] + xv[3];
    __syncthreads();
    if (t < 256) {
        const int a = t >> 4;
        sA[a][q] = part[4*a][q] + part[4*a+1][q] + part[4*a+2][q] + part[4*a+3][q];
    }
    __syncthreads();
    if (t < 256) {
        const int k = t >> 4;
        f32x4 ssum = (f32x4)(0.f);
        #pragma unroll
        for (int i = 0; i < 16; ++i) ssum += sA[i][q];
        ssum *= (1.0f / (float)NC);
        const float w1k = w1[k], b1k = b1[k];
        f32x4 hv;
        hv.x = fmaxf(fmaf(ssum.x, w1k, b1k), 0.f);
        hv.y = fmaxf(fmaf(ssum.y, w1k, b1k), 0.f);
        hv.z = fmaxf(fmaf(ssum.z, w1k, b1k), 0.f);
        hv.w = fmaxf(fmaf(ssum.w, w1k, b1k), 0.f);
        hv4[k][q] = hv;
    }
    __syncthreads();

    f32x4 acc[4];
    #pragma unroll
    for (int i = 0; i < 4; ++i) acc[i] = (f32x4)(b2s[(cg << 2) + i]);
    #pragma unroll
    for (int k = 0; k < NK; ++k) {
        const f32x4 hk = hv4[k][q];
        const f32x4 wv = *reinterpret_cast<const f32x4*>(&w2t[k][cg << 2]);
        acc[0] += hk * wv.x; acc[1] += hk * wv.y;
        acc[2] += hk * wv.z; acc[3] += hk * wv.w;
    }
    #pragma unroll
    for (int i = 0; i < 4; ++i) {
        const f32x4 xvv = xv[i];
        f32x4 r;
        r.x = xvv.x * fsig(acc[i].x);
        r.y = xvv.y * fsig(acc[i].y);
        r.z = xvv.z * fsig(acc[i].z);
        r.w = xvv.w * fsig(acc[i].w);
        __builtin_nontemporal_store(r,
            reinterpret_cast<f32x4*>(op + (size_t)((cg << 2) + i) * HW + (q << 2)));
    }
}

extern "C" void kernel_launch(void* const* d_in, const int* in_sizes, int n_in,
                              void* d_out, int out_size, void* d_ws, size_t ws_size,
                              hipStream_t stream) {
    const float* x  = (const float*)d_in[0];
    const float* w1 = (const float*)d_in[1];
    const float* b1 = (const float*)d_in[2];
    const float* w2 = (const float*)d_in[3];
    const float* b2 = (const float*)d_in[4];
    float* out = (float*)d_out;

    const size_t s_bytes = (size_t)NB * NH * NW * sizeof(float);  // 512 KiB
    if (ws_size >= s_bytes) {
        float* s = (float*)d_ws;
        hipLaunchKernelGGL(pse_mean,  dim3(NB * NH), dim3(256), 0, stream, x, s);
        hipLaunchKernelGGL(pse_apply, dim3(NB * NH), dim3(256), 0, stream,
                           x, s, w1, b1, w2, b2, out);
    } else {
        hipLaunchKernelGGL(pse_fused, dim3(NB * NH), dim3(1024), 0, stream,
                           x, w1, b1, w2, b2, out);
    }
}

// Round 6
// 234.639 us; speedup vs baseline: 1.1039x; 1.1039x over previous
//
#include <hip/hip_runtime.h>

#define NB 32
#define NC 256
#define NH 64
#define NW 64
#define NK 16
#define HW (NH * NW)      // 4096
#define NIT 8             // h-rows per block
#define NBLK (NB * NH / NIT)  // 256 blocks = 1 per CU

typedef float f32x4 __attribute__((ext_vector_type(4)));

__device__ __forceinline__ float fsig(float z) {
    // sigmoid(z) = 1/(1+exp(-z)); fast exp + hw rcp (vs 5.9e-2 threshold: plenty)
    return __builtin_amdgcn_rcpf(1.0f + __expf(-z));
}

// 1024 threads; thread (cg=t>>4 in 0..63, q=t&15) owns channels 4cg..4cg+3 x w-quad q.
// Software pipeline over NIT rows: loads of row it+1 issued before the reduce/store
// of row it, so the memory pipe never drains during the barrier/MLP phase.
__global__ __launch_bounds__(1024, 4) void pse_kernel(
    const float* __restrict__ x,
    const float* __restrict__ w1,
    const float* __restrict__ b1,
    const float* __restrict__ w2,
    const float* __restrict__ b2,
    float* __restrict__ out)
{
    __shared__ float w2t[NK][NC + 4];  // w2 transposed -> w2t[k][c]
    __shared__ f32x4 part[16][17];     // per-wave folded partial sums [wave][q]
    __shared__ f32x4 hv4[NK][16];      // hidden layer hv[k][q]
    __shared__ float b2s[NC];

    const int t   = threadIdx.x;
    const int cg  = t >> 4;   // 0..63 : 4-channel group
    const int q   = t & 15;   // 0..15 : w-quad
    const int wid = t >> 6;   // 0..15 : wave id
    const int blk = blockIdx.x;

    // ---- one-time staging: w2 transposed + b2; per-thread MLP params for stage B
    {
        const f32x4 v = reinterpret_cast<const f32x4*>(w2)[t];  // 1024 float4
        const int c  = t >> 2;
        const int k0 = (t & 3) << 2;
        w2t[k0 + 0][c] = v.x; w2t[k0 + 1][c] = v.y;
        w2t[k0 + 2][c] = v.z; w2t[k0 + 3][c] = v.w;
        if (t < NC) b2s[t] = b2[t];
    }
    float w1k = 0.f, b1k = 0.f;
    if (t < 256) { const int k = t >> 4; w1k = w1[k]; b1k = b1[k]; }

    // row base pointers: bh = it*NBLK + blk (concurrent rows are adjacent in memory)
    const size_t lane_off = (size_t)(cg << 2) * HW + (q << 2);

    f32x4 xv[2][4];   // ping-pong register buffers (it fully unrolled -> static idx)

#define ROWPTR(IT, BASE) \
    ((BASE) + (size_t)((((IT) << 8) + blk) >> 6) * NC * HW \
            + (size_t)((((IT) << 8) + blk) & 63) * NW + lane_off)

#define LOADROW(BUF, IT) { \
    const float* _p = ROWPTR(IT, x); \
    _Pragma("unroll") \
    for (int _i = 0; _i < 4; ++_i) \
        BUF[_i] = __builtin_nontemporal_load( \
            reinterpret_cast<const f32x4*>(_p + (size_t)_i * HW)); }

    // prologue: row 0 in flight
    LOADROW(xv[0], 0)

    #pragma unroll
    for (int it = 0; it < NIT; ++it) {
        const int cur = it & 1, nxt = cur ^ 1;

        // issue next row's loads first — they fly during the reduce/MLP/store below
        if (it + 1 < NIT) LOADROW(xv[nxt], it + 1)

        // ---- partial channel sum + in-wave fold (4 cg groups per wave)
        {
            f32x4 p = xv[cur][0] + xv[cur][1] + xv[cur][2] + xv[cur][3];
            p.x += __shfl_xor(p.x, 16, 64); p.y += __shfl_xor(p.y, 16, 64);
            p.z += __shfl_xor(p.z, 16, 64); p.w += __shfl_xor(p.w, 16, 64);
            p.x += __shfl_xor(p.x, 32, 64); p.y += __shfl_xor(p.y, 32, 64);
            p.z += __shfl_xor(p.z, 32, 64); p.w += __shfl_xor(p.w, 32, 64);
            if ((t & 63) < 16) part[wid][q] = p;
        }
        __syncthreads();

        // ---- final mean + hidden layer: thread (k=t>>4, q) for t<256
        if (t < 256) {
            f32x4 s = (f32x4)(0.f);
            #pragma unroll
            for (int i = 0; i < 16; ++i) s += part[i][q];   // broadcast reads
            s *= (1.0f / (float)NC);
            f32x4 hv;
            hv.x = fmaxf(fmaf(s.x, w1k, b1k), 0.f);
            hv.y = fmaxf(fmaf(s.y, w1k, b1k), 0.f);
            hv.z = fmaxf(fmaf(s.z, w1k, b1k), 0.f);
            hv.w = fmaxf(fmaf(s.w, w1k, b1k), 0.f);
            hv4[t >> 4][q] = hv;
        }
        __syncthreads();

        // ---- logits for 4 channels x quad, gate, store
        {
            f32x4 acc0 = (f32x4)(b2s[(cg << 2) + 0]);
            f32x4 acc1 = (f32x4)(b2s[(cg << 2) + 1]);
            f32x4 acc2 = (f32x4)(b2s[(cg << 2) + 2]);
            f32x4 acc3 = (f32x4)(b2s[(cg << 2) + 3]);
            #pragma unroll
            for (int k = 0; k < NK; ++k) {
                const f32x4 hk = hv4[k][q];
                const f32x4 wvv = *reinterpret_cast<const f32x4*>(&w2t[k][cg << 2]);
                acc0 += hk * wvv.x; acc1 += hk * wvv.y;
                acc2 += hk * wvv.z; acc3 += hk * wvv.w;
            }
            float* _o = const_cast<float*>(ROWPTR(it, out));
            const f32x4 xc0 = xv[cur][0], xc1 = xv[cur][1];
            const f32x4 xc2 = xv[cur][2], xc3 = xv[cur][3];
            f32x4 r;
            r.x = xc0.x * fsig(acc0.x); r.y = xc0.y * fsig(acc0.y);
            r.z = xc0.z * fsig(acc0.z); r.w = xc0.w * fsig(acc0.w);
            __builtin_nontemporal_store(r, reinterpret_cast<f32x4*>(_o + 0 * (size_t)HW));
            r.x = xc1.x * fsig(acc1.x); r.y = xc1.y * fsig(acc1.y);
            r.z = xc1.z * fsig(acc1.z); r.w = xc1.w * fsig(acc1.w);
            __builtin_nontemporal_store(r, reinterpret_cast<f32x4*>(_o + 1 * (size_t)HW));
            r.x = xc2.x * fsig(acc2.x); r.y = xc2.y * fsig(acc2.y);
            r.z = xc2.z * fsig(acc2.z); r.w = xc2.w * fsig(acc2.w);
            __builtin_nontemporal_store(r, reinterpret_cast<f32x4*>(_o + 2 * (size_t)HW));
            r.x = xc3.x * fsig(acc3.x); r.y = xc3.y * fsig(acc3.y);
            r.z = xc3.z * fsig(acc3.z); r.w = xc3.w * fsig(acc3.w);
            __builtin_nontemporal_store(r, reinterpret_cast<f32x4*>(_o + 3 * (size_t)HW));
        }
    }
#undef LOADROW
#undef ROWPTR
}

extern "C" void kernel_launch(void* const* d_in, const int* in_sizes, int n_in,
                              void* d_out, int out_size, void* d_ws, size_t ws_size,
                              hipStream_t stream) {
    const float* x  = (const float*)d_in[0];
    const float* w1 = (const float*)d_in[1];
    const float* b1 = (const float*)d_in[2];
    const float* w2 = (const float*)d_in[3];
    const float* b2 = (const float*)d_in[4];
    float* out = (float*)d_out;

    hipLaunchKernelGGL(pse_kernel, dim3(NBLK), dim3(1024), 0, stream,
                       x, w1, b1, w2, b2, out);
}